// Round 2
// baseline (382.803 us; speedup 1.0000x reference)
//
#include <hip/hip_runtime.h>
#include <math.h>

#define CLASSNUM 70722
#define BATCH 512
#define EMBD 512
#define M_C 0.4f
#define H_C 0.333f
#define S_C 64.0f
#define EPS_C 0.001f
#define PI_F 3.14159265358979f

typedef __bf16 bf16_t;
typedef __bf16 bf16x8 __attribute__((ext_vector_type(8)));
typedef float f32x4 __attribute__((ext_vector_type(4)));

__device__ __forceinline__ float clampf(float x, float lo, float hi) {
    return fminf(fmaxf(x, lo), hi);
}

// ---------------------------------------------------------------------------
// prep_lab: fused.
//   blocks 0..127  : convert embeddings fp32 -> bf16 into workspace, stored in
//                    MFMA-fragment order: fragment F(kt, rg) covers rows
//                    [rg*16, rg*16+16) x k [kt*32, kt*32+32); granule
//                    g = (kt*32+rg)*64 + lane holds row rg*16+(lane&15),
//                    k-octet (lane>>4).  1 KB contiguous per fragment so the
//                    gemm reads each fragment with ONE coalesced dwordx4.
//   blocks 128..639: b = bi-128.  Redundantly recompute batch mean/std of
//                    safe_norms (4 KB of L2-hot loads), then exact fp32
//                    dot(emb[b], K[:,label[b]]) + column norm + full margin
//                    formula -> labout[b].  Removes the prep->lab kernel
//                    dependency so 4 launches collapse to 2.
// ---------------------------------------------------------------------------
__global__ __launch_bounds__(256) void prep_lab_kernel(
    const float* __restrict__ emb, const float* __restrict__ norms,
    const float* __restrict__ csn, const int* __restrict__ label,
    const float* __restrict__ kmat, bf16_t* __restrict__ Aws,
    float* __restrict__ labout)
{
    __shared__ float red[256];
    const int tid = threadIdx.x;
    const int bi = blockIdx.x;

    if (bi < 128) {
        const int G = bi * 256 + tid;           // granule id, 0..32767
        const int kt = G >> 11;                 // k-slab (32 k per slab)
        const int rem = G & 2047;
        const int rg = rem >> 6;                // 16-row group, 0..31
        const int lane = rem & 63;
        const int row = rg * 16 + (lane & 15);
        const int k0 = kt * 32 + (lane >> 4) * 8;
        const float* src = emb + row * EMBD + k0;
        const float4 v0 = *(const float4*)src;
        const float4 v1 = *(const float4*)(src + 4);
        bf16x8 bw;
        bw[0] = (bf16_t)v0.x; bw[1] = (bf16_t)v0.y;
        bw[2] = (bf16_t)v0.z; bw[3] = (bf16_t)v0.w;
        bw[4] = (bf16_t)v1.x; bw[5] = (bf16_t)v1.y;
        bw[6] = (bf16_t)v1.z; bw[7] = (bf16_t)v1.w;
        *(bf16x8*)(Aws + (size_t)G * 8) = bw;   // coalesced 16 B store
        return;
    }

    const int b = bi - 128;

    // ---- batch stats over safe_norms (redundant per block, trivial) ----
    float s0, s1;
    {
        float sn = clampf(norms[tid], 0.001f, 100.0f);
        sn = sn / (csn[tid] + 0.001f);
        s0 = clampf(sn, 0.001f, 100.0f);
    }
    {
        float sn = clampf(norms[tid + 256], 0.001f, 100.0f);
        sn = sn / (csn[tid + 256] + 0.001f);
        s1 = clampf(sn, 0.001f, 100.0f);
    }
    red[tid] = s0 + s1;
    __syncthreads();
    for (int off = 128; off > 0; off >>= 1) {
        if (tid < off) red[tid] += red[tid + off];
        __syncthreads();
    }
    const float mean = red[0] * (1.0f / 512.0f);
    __syncthreads();
    const float d0 = s0 - mean, d1 = s1 - mean;
    red[tid] = d0 * d0 + d1 * d1;
    __syncthreads();
    for (int off = 128; off > 0; off >>= 1) {
        if (tid < off) red[tid] += red[tid + off];
        __syncthreads();
    }
    const float stdv = sqrtf(red[0] * (1.0f / 511.0f));   // ddof=1
    __syncthreads();

    // ---- exact fp32 dot + column sum-square for this row's label ----
    const int lab = label[b];
    const float* col = kmat + lab;
    const float* e = emb + b * EMBD;
    float dot = 0.0f, ss = 0.0f;
#pragma unroll
    for (int k = tid; k < EMBD; k += 256) {
        const float kv = col[(size_t)k * CLASSNUM];
        const float ev = e[k];
        dot = fmaf(ev, kv, dot);
        ss  = fmaf(kv, kv, ss);
    }
    red[tid] = dot;
    __syncthreads();
    for (int off = 128; off > 0; off >>= 1) {
        if (tid < off) red[tid] += red[tid + off];
        __syncthreads();
    }
    const float dotT = red[0];
    __syncthreads();
    red[tid] = ss;
    __syncthreads();
    for (int off = 128; off > 0; off >>= 1) {
        if (tid < off) red[tid] += red[tid + off];
        __syncthreads();
    }
    if (tid == 0) {
        const float ssT = red[0];
        float c = dotT / sqrtf(ssT);
        c = clampf(c, -1.0f + EPS_C, 1.0f - EPS_C);
        float snb = clampf(norms[b], 0.001f, 100.0f);
        snb = snb / (csn[b] + 0.001f);
        snb = clampf(snb, 0.001f, 100.0f);
        const float msv = clampf((snb - mean) / (stdv + EPS_C) * H_C, -1.0f, 1.0f);
        float th = acosf(c) - M_C * msv;
        th = clampf(th, EPS_C, PI_F - EPS_C);
        labout[b] = (cosf(th) - (M_C + M_C * msv)) * S_C;
    }
}

// ---------------------------------------------------------------------------
// gemm: barrier-free streaming GEMM.  Grid = 1106 blocks x 512 threads.
// Block covers MT=512 (whole batch, so K is read from HBM exactly once) x
// NT=64 columns.  Wave w owns rows [w*64, w*64+64) -- waves share NOTHING,
// so the K-loop has ZERO __syncthreads: each wave streams B fragments from
// HBM into registers (2 iterations deep, compiler-counted vmcnt) and its own
// pre-fragmented A from L2 with one dwordx4 per fragment.  No lockstep
// drains; 8 independent waves/CU keep the HBM queue full.
// Scatter is folded into the epilogue via LDS label/labout tables.
// ---------------------------------------------------------------------------

#define LOADB(kt, bv) do {                                              \
    const size_t kb_ = (size_t)((kt) * 32) * CLASSNUM;                  \
    _Pragma("unroll")                                                   \
    for (int ni_ = 0; ni_ < 4; ++ni_) {                                 \
        _Pragma("unroll")                                               \
        for (int j_ = 0; j_ < 8; ++j_)                                  \
            bv[ni_][j_] = bq[ni_][kb_ + (size_t)j_ * CLASSNUM];         \
    }                                                                   \
} while (0)

#define LOADA(kt, af) do {                                              \
    const bf16x8* ap_ = (const bf16x8*)Aws                              \
        + (((kt) * 32 + wave * 4) * 64 + lane);                         \
    _Pragma("unroll")                                                   \
    for (int mi_ = 0; mi_ < 4; ++mi_) af[mi_] = ap_[mi_ * 64];          \
} while (0)

#define CVTB(bv, bfr) do {                                              \
    _Pragma("unroll")                                                   \
    for (int ni_ = 0; ni_ < 4; ++ni_) {                                 \
        _Pragma("unroll")                                               \
        for (int j_ = 0; j_ < 8; ++j_) {                                \
            const float v_ = bv[ni_][j_];                               \
            ssq[ni_] = fmaf(v_, v_, ssq[ni_]);                          \
            bfr[ni_][j_] = (bf16_t)v_;                                  \
        }                                                               \
    }                                                                   \
} while (0)

#define DOMFMA(af, bfr) do {                                            \
    _Pragma("unroll")                                                   \
    for (int mi_ = 0; mi_ < 4; ++mi_) {                                 \
        _Pragma("unroll")                                               \
        for (int ni_ = 0; ni_ < 4; ++ni_)                               \
            acc[mi_][ni_] = __builtin_amdgcn_mfma_f32_16x16x32_bf16(    \
                af[mi_], bfr[ni_], acc[mi_][ni_], 0, 0, 0);             \
    }                                                                   \
} while (0)

__global__ __launch_bounds__(512, 2) void gemm_kernel(
    const bf16_t* __restrict__ Aws, const float* __restrict__ Kmat,
    const int* __restrict__ label, const float* __restrict__ labout,
    float* __restrict__ out)
{
    __shared__ int   lab_s[BATCH];
    __shared__ float lo_s[BATCH];
    const int tid = threadIdx.x;
    lab_s[tid] = label[tid];
    lo_s[tid]  = labout[tid];
    __syncthreads();        // the only block-wide barrier

    const int lane = tid & 63;
    const int wave = tid >> 6;          // 0..7 -> M split, 64 rows each
    const int r16  = lane & 15;
    const int quad = lane >> 4;
    const int n0   = blockIdx.x * 64;

    // Per-lane B column base pointers in fragment layout:
    // col(ni) = n0 + ni*16 + r16 (clamped in-bounds; stores are guarded),
    // k-octet = quad.  Load (kt,j): bq[ni][(kt*32 + j)*CLASSNUM].
    const float* bq[4];
    bool cok[4];
#pragma unroll
    for (int ni = 0; ni < 4; ++ni) {
        int c = n0 + ni * 16 + r16;
        cok[ni] = (c < CLASSNUM);
        c = cok[ni] ? c : (CLASSNUM - 1);
        bq[ni] = Kmat + (size_t)(quad * 8) * CLASSNUM + c;
    }

    f32x4 acc[4][4];
    const f32x4 zero = {0.0f, 0.0f, 0.0f, 0.0f};
#pragma unroll
    for (int i = 0; i < 4; ++i)
#pragma unroll
        for (int j = 0; j < 4; ++j) acc[i][j] = zero;
    float ssq[4] = {0.0f, 0.0f, 0.0f, 0.0f};

    float bvA[4][8], bvB[4][8];
    bf16x8 afC[4], afN[4];

    // ---- prologue: B 2 iterations deep, A 1 deep ----
    LOADB(0, bvA);
    LOADB(1, bvB);
    LOADA(0, afC);

#pragma unroll 1
    for (int p = 0; p < 7; ++p) {
        {   // it = 2p : consume bvA/afC, refill bvA (it+2), afN (it+1)
            bf16x8 bfr[4];
            CVTB(bvA, bfr);
            LOADB(2 * p + 2, bvA);
            LOADA(2 * p + 1, afN);
            DOMFMA(afC, bfr);
        }
        {   // it = 2p+1 : consume bvB/afN, refill bvB (it+2), afC (it+1)
            bf16x8 bfr[4];
            CVTB(bvB, bfr);
            LOADB(2 * p + 3, bvB);
            LOADA(2 * p + 2, afC);
            DOMFMA(afN, bfr);
        }
    }
    {   // it = 14
        bf16x8 bfr[4];
        CVTB(bvA, bfr);
        LOADA(15, afN);
        DOMFMA(afC, bfr);
    }
    {   // it = 15
        bf16x8 bfr[4];
        CVTB(bvB, bfr);
        DOMFMA(afN, bfr);
    }

    // ---- column inverse norms: every wave loaded the full column, only a
    // cross-quad reduce is needed (lanes l, l^16, l^32, l^48 share a col).
    float invn[4];
#pragma unroll
    for (int ni = 0; ni < 4; ++ni) {
        float s = ssq[ni];
        s += __shfl_xor(s, 16);
        s += __shfl_xor(s, 32);
        invn[ni] = (s > 0.0f) ? (1.0f / sqrtf(s)) : 0.0f;
    }

    // ---- epilogue: out = S * clip(c); label entry substituted in-place
    // (scatter kernel folded in; each (row, label[row]) belongs to exactly
    // one block).  lab_s/lo_s reads are uniform per 16-lane group ->
    // LDS broadcast, conflict-free.
#pragma unroll
    for (int mi = 0; mi < 4; ++mi) {
#pragma unroll
        for (int rr = 0; rr < 4; ++rr) {
            const int row = wave * 64 + mi * 16 + quad * 4 + rr;
            const int labc = lab_s[row];
            const float lov = lo_s[row];
            float* orow = out + (size_t)row * CLASSNUM;
#pragma unroll
            for (int ni = 0; ni < 4; ++ni) {
                if (cok[ni]) {
                    const int col = n0 + ni * 16 + r16;
                    const float c = clampf(acc[mi][ni][rr] * invn[ni],
                                           -1.0f + EPS_C, 1.0f - EPS_C);
                    float v = c * S_C;
                    if (labc == col) v = lov;
                    orow[col] = v;
                }
            }
        }
    }
}

extern "C" void kernel_launch(void* const* d_in, const int* in_sizes, int n_in,
                              void* d_out, int out_size, void* d_ws, size_t ws_size,
                              hipStream_t stream)
{
    const float* emb   = (const float*)d_in[0];
    const float* norms = (const float*)d_in[1];
    const int*   label = (const int*)d_in[2];
    const float* csn   = (const float*)d_in[3];
    const float* kmat  = (const float*)d_in[4];
    float* out = (float*)d_out;

    // workspace: [A bf16 fragment-tiled 512x512 | labout 512]
    const size_t A_BYTES = (size_t)BATCH * EMBD * sizeof(bf16_t);  // 524288
    if (ws_size < A_BYTES + 4096) return;
    bf16_t* Aws   = (bf16_t*)d_ws;
    float* labout = (float*)((char*)d_ws + A_BYTES);

    prep_lab_kernel<<<128 + BATCH, 256, 0, stream>>>(
        emb, norms, csn, label, kmat, Aws, labout);
    const int nblk = (CLASSNUM + 63) / 64;   // 1106
    gemm_kernel<<<nblk, 512, 0, stream>>>(Aws, kmat, label, labout, out);
}

// Round 3
// 316.970 us; speedup vs baseline: 1.2077x; 1.2077x over previous
//
#include <hip/hip_runtime.h>
#include <math.h>

#define CLASSNUM 70722
#define BATCH 512
#define EMBD 512
#define M_C 0.4f
#define H_C 0.333f
#define S_C 64.0f
#define EPS_C 0.001f
#define PI_F 3.14159265358979f

typedef __bf16 bf16_t;
typedef __bf16 bf16x4 __attribute__((ext_vector_type(4)));
typedef __bf16 bf16x8 __attribute__((ext_vector_type(8)));
typedef float f32x4 __attribute__((ext_vector_type(4)));

__device__ __forceinline__ float clampf(float x, float lo, float hi) {
    return fminf(fmaxf(x, lo), hi);
}

// ---------------------------------------------------------------------------
// prep_lab (unchanged from r2, verified): blocks 0..127 convert emb fp32->bf16
// into MFMA-fragment order; blocks 128..639 compute the exact fp32 label
// column values (margin formula) into labout.
// ---------------------------------------------------------------------------
__global__ __launch_bounds__(256) void prep_lab_kernel(
    const float* __restrict__ emb, const float* __restrict__ norms,
    const float* __restrict__ csn, const int* __restrict__ label,
    const float* __restrict__ kmat, bf16_t* __restrict__ Aws,
    float* __restrict__ labout)
{
    __shared__ float red[256];
    const int tid = threadIdx.x;
    const int bi = blockIdx.x;

    if (bi < 128) {
        const int G = bi * 256 + tid;           // granule id, 0..32767
        const int kt = G >> 11;                 // k-slab (32 k per slab)
        const int rem = G & 2047;
        const int rg = rem >> 6;                // 16-row group, 0..31
        const int lane = rem & 63;
        const int row = rg * 16 + (lane & 15);
        const int k0 = kt * 32 + (lane >> 4) * 8;
        const float* src = emb + row * EMBD + k0;
        const float4 v0 = *(const float4*)src;
        const float4 v1 = *(const float4*)(src + 4);
        bf16x8 bw;
        bw[0] = (bf16_t)v0.x; bw[1] = (bf16_t)v0.y;
        bw[2] = (bf16_t)v0.z; bw[3] = (bf16_t)v0.w;
        bw[4] = (bf16_t)v1.x; bw[5] = (bf16_t)v1.y;
        bw[6] = (bf16_t)v1.z; bw[7] = (bf16_t)v1.w;
        *(bf16x8*)(Aws + (size_t)G * 8) = bw;   // coalesced 16 B store
        return;
    }

    const int b = bi - 128;

    float s0, s1;
    {
        float sn = clampf(norms[tid], 0.001f, 100.0f);
        sn = sn / (csn[tid] + 0.001f);
        s0 = clampf(sn, 0.001f, 100.0f);
    }
    {
        float sn = clampf(norms[tid + 256], 0.001f, 100.0f);
        sn = sn / (csn[tid + 256] + 0.001f);
        s1 = clampf(sn, 0.001f, 100.0f);
    }
    red[tid] = s0 + s1;
    __syncthreads();
    for (int off = 128; off > 0; off >>= 1) {
        if (tid < off) red[tid] += red[tid + off];
        __syncthreads();
    }
    const float mean = red[0] * (1.0f / 512.0f);
    __syncthreads();
    const float d0 = s0 - mean, d1 = s1 - mean;
    red[tid] = d0 * d0 + d1 * d1;
    __syncthreads();
    for (int off = 128; off > 0; off >>= 1) {
        if (tid < off) red[tid] += red[tid + off];
        __syncthreads();
    }
    const float stdv = sqrtf(red[0] * (1.0f / 511.0f));   // ddof=1
    __syncthreads();

    const int lab = label[b];
    const float* col = kmat + lab;
    const float* e = emb + b * EMBD;
    float dot = 0.0f, ss = 0.0f;
#pragma unroll
    for (int k = tid; k < EMBD; k += 256) {
        const float kv = col[(size_t)k * CLASSNUM];
        const float ev = e[k];
        dot = fmaf(ev, kv, dot);
        ss  = fmaf(kv, kv, ss);
    }
    red[tid] = dot;
    __syncthreads();
    for (int off = 128; off > 0; off >>= 1) {
        if (tid < off) red[tid] += red[tid + off];
        __syncthreads();
    }
    const float dotT = red[0];
    __syncthreads();
    red[tid] = ss;
    __syncthreads();
    for (int off = 128; off > 0; off >>= 1) {
        if (tid < off) red[tid] += red[tid + off];
        __syncthreads();
    }
    if (tid == 0) {
        const float ssT = red[0];
        float c = dotT / sqrtf(ssT);
        c = clampf(c, -1.0f + EPS_C, 1.0f - EPS_C);
        float snb = clampf(norms[b], 0.001f, 100.0f);
        snb = snb / (csn[b] + 0.001f);
        snb = clampf(snb, 0.001f, 100.0f);
        const float msv = clampf((snb - mean) / (stdv + EPS_C) * H_C, -1.0f, 1.0f);
        float th = acosf(c) - M_C * msv;
        th = clampf(th, EPS_C, PI_F - EPS_C);
        labout[b] = (cosf(th) - (M_C + M_C * msv)) * S_C;
    }
}

// ---------------------------------------------------------------------------
// gemm v3: MT=512 x NT=64 per block (K read from HBM once), 8 waves, wave-tile
// 64x64 (acc=64).  B staged cooperatively (no redundancy): thread (c=tid&63,
// kg=tid>>6) loads 4 strided dwords per K-step, TWO steps ahead, converts to
// bf16 into a double-buffered Blds.  Raw s_barrier + lgkmcnt(0) only -- the
// in-flight B(it+2) loads cross the barrier (compiler dep-wait is vmcnt(4)
// because A loads are issued FIRST each iteration).  A fragments come per-wave
// from the fragment-ordered workspace (L2-hot, one dwordx4 each).
// __launch_bounds__(512,4) targets <=128 regs -> 2 blocks/CU = 16 waves/CU.
// Scatter + column-norm epilogue fused.
// ---------------------------------------------------------------------------

#define LOADB4(t, dst) do {                                             \
    const size_t ko_ = (size_t)((t) * 32) * CLASSNUM;                   \
    _Pragma("unroll")                                                   \
    for (int j_ = 0; j_ < 4; ++j_)                                      \
        dst[j_] = bp[ko_ + (size_t)j_ * CLASSNUM];                      \
} while (0)

#define LOADA4(t, af) do {                                              \
    const bf16x8* ap_ = (const bf16x8*)Aws                              \
        + (((t) * 32 + wave * 4) * 64 + lane);                          \
    _Pragma("unroll")                                                   \
    for (int mi_ = 0; mi_ < 4; ++mi_) af[mi_] = ap_[mi_ * 64];          \
} while (0)

#define CVTW(src, buf) do {                                             \
    bf16x4 w_;                                                          \
    _Pragma("unroll")                                                   \
    for (int j_ = 0; j_ < 4; ++j_) {                                    \
        const float v_ = src[j_];                                       \
        ssq = fmaf(v_, v_, ssq);                                        \
        w_[j_] = (bf16_t)v_;                                            \
    }                                                                   \
    *(bf16x4*)&Blds[buf][c * 40 + kg * 4] = w_;                         \
} while (0)

#define MFMA16(af, buf) do {                                            \
    bf16x8 bfr_[4];                                                     \
    _Pragma("unroll")                                                   \
    for (int ni_ = 0; ni_ < 4; ++ni_)                                   \
        bfr_[ni_] = *(const bf16x8*)                                    \
            &Blds[buf][(ni_ * 16 + r16) * 40 + quad * 8];               \
    _Pragma("unroll")                                                   \
    for (int mi_ = 0; mi_ < 4; ++mi_)                                   \
        _Pragma("unroll")                                               \
        for (int ni_ = 0; ni_ < 4; ++ni_)                               \
            acc[mi_][ni_] = __builtin_amdgcn_mfma_f32_16x16x32_bf16(    \
                af[mi_], bfr_[ni_], acc[mi_][ni_], 0, 0, 0);            \
} while (0)

#define BARRIER() do {                                                  \
    asm volatile("s_waitcnt lgkmcnt(0)" ::: "memory");                  \
    __builtin_amdgcn_s_barrier();                                       \
} while (0)

__global__ __launch_bounds__(512, 4) void gemm_kernel(
    const bf16_t* __restrict__ Aws, const float* __restrict__ Kmat,
    const int* __restrict__ label, const float* __restrict__ labout,
    float* __restrict__ out)
{
    __shared__ bf16_t Blds[2][64 * 40];     // padded stride 40 (80 B, 16-align)
    __shared__ float red[512];
    __shared__ float invn_s[64];
    __shared__ int   lab_s[BATCH];
    __shared__ float lo_s[BATCH];

    const int tid  = threadIdx.x;
    const int lane = tid & 63;
    const int wave = tid >> 6;
    const int r16  = lane & 15;
    const int quad = lane >> 4;

    // bijective XCD swizzle (nwg=1106 = 8*138+2): same-XCD blocks get
    // contiguous column windows -> L2/L3 locality for A and out.
    const int nwg = (CLASSNUM + 63) / 64;
    const int q_ = nwg >> 3, r_ = nwg & 7;
    const int xcd = blockIdx.x & 7, idx = blockIdx.x >> 3;
    const int nb = (xcd < r_) ? (xcd * (q_ + 1) + idx)
                              : (r_ * (q_ + 1) + (xcd - r_) * q_ + idx);
    const int n0 = nb * 64;

    lab_s[tid] = label[tid];
    lo_s[tid]  = labout[tid];

    // B cooperative-load ownership: col c (0..63), k-group kg (0..7).
    const int c  = tid & 63;
    const int kg = tid >> 6;
    int cg = n0 + c;
    const bool cv = (cg < CLASSNUM);
    if (!cv) cg = CLASSNUM - 1;              // clamp; stores are guarded
    const float* bp = Kmat + (size_t)(kg * 4) * CLASSNUM + cg;

    f32x4 acc[4][4];
    const f32x4 zero = {0.0f, 0.0f, 0.0f, 0.0f};
#pragma unroll
    for (int i = 0; i < 4; ++i)
#pragma unroll
        for (int j = 0; j < 4; ++j) acc[i][j] = zero;
    float ssq = 0.0f;

    float bv0[4], bv1[4];

    // ---- prologue: B(0)->bv0, B(1)->bv1, stage B(0) into Blds[0] ----
    LOADB4(0, bv0);
    LOADB4(1, bv1);
    CVTW(bv0, 0);
    BARRIER();

    // ---- K loop, hand-unrolled x2 (static buffer names; rule #20) ----
    // Per sub-iter: LOADA first, then LOADB(it+2) -> compiler's MFMA
    // dep-wait is vmcnt(4), leaving B(it+2) in flight across the barrier.
#pragma unroll 1
    for (int p = 0; p < 8; ++p) {
        {   // it = 2p (even, reads Blds[0]; CVT bv1=B(2p+1) -> Blds[1])
            bf16x8 af[4];
            LOADA4(2 * p, af);
            if (p < 7) LOADB4(2 * p + 2, bv0);
            MFMA16(af, 0);
            CVTW(bv1, 1);
            BARRIER();
        }
        {   // it = 2p+1 (odd, reads Blds[1]; CVT bv0=B(2p+2) -> Blds[0])
            bf16x8 af[4];
            LOADA4(2 * p + 1, af);
            if (p < 7) LOADB4(2 * p + 3, bv1);
            MFMA16(af, 1);
            if (p < 7) CVTW(bv0, 0);
            BARRIER();
        }
    }

    // ---- column inverse norms: ssq partials live on 8 threads per col ----
    red[tid] = ssq;
    __syncthreads();
    if (tid < 64) {
        float s = 0.0f;
#pragma unroll
        for (int g = 0; g < 8; ++g) s += red[tid + g * 64];
        invn_s[tid] = (s > 0.0f) ? (1.0f / sqrtf(s)) : 0.0f;
    }
    __syncthreads();

    // ---- epilogue: out = S * clip(cosine); label entries substituted ----
#pragma unroll
    for (int mi = 0; mi < 4; ++mi) {
#pragma unroll
        for (int rr = 0; rr < 4; ++rr) {
            const int row = wave * 64 + mi * 16 + quad * 4 + rr;
            const int labc = lab_s[row];
            const float lov = lo_s[row];
            float* orow = out + (size_t)row * CLASSNUM;
#pragma unroll
            for (int ni = 0; ni < 4; ++ni) {
                const int col_loc = ni * 16 + r16;
                const int col = n0 + col_loc;
                if (col < CLASSNUM) {
                    const float cc = clampf(acc[mi][ni][rr] * invn_s[col_loc],
                                            -1.0f + EPS_C, 1.0f - EPS_C);
                    float v = cc * S_C;
                    if (labc == col) v = lov;
                    orow[col] = v;
                }
            }
        }
    }
}

extern "C" void kernel_launch(void* const* d_in, const int* in_sizes, int n_in,
                              void* d_out, int out_size, void* d_ws, size_t ws_size,
                              hipStream_t stream)
{
    const float* emb   = (const float*)d_in[0];
    const float* norms = (const float*)d_in[1];
    const int*   label = (const int*)d_in[2];
    const float* csn   = (const float*)d_in[3];
    const float* kmat  = (const float*)d_in[4];
    float* out = (float*)d_out;

    // workspace: [A bf16 fragment-tiled 512x512 | labout 512]
    const size_t A_BYTES = (size_t)BATCH * EMBD * sizeof(bf16_t);  // 524288
    if (ws_size < A_BYTES + 4096) return;
    bf16_t* Aws   = (bf16_t*)d_ws;
    float* labout = (float*)((char*)d_ws + A_BYTES);

    prep_lab_kernel<<<128 + BATCH, 256, 0, stream>>>(
        emb, norms, csn, label, kmat, Aws, labout);
    const int nblk = (CLASSNUM + 63) / 64;   // 1106
    gemm_kernel<<<nblk, 512, 0, stream>>>(Aws, kmat, label, labout, out);
}